// Round 1
// 149.053 us; speedup vs baseline: 1.0455x; 1.0455x over previous
//
#include <hip/hip_runtime.h>

// PureMul32 circuit, algebraically collapsed.
//
// Per token (b,p), with constants a=x[OPMUL], na=x[NIB_A], nb=x[NIB_B],
// ci=x[CARRY_IN], p=position:
//   r0   = x[RESULT]*(1-a)
//   t   += nb * 1.875 * (p+1)^2 / 2                      (TEMP, never read back)
//   for i in 0..31:  npos=i/4, bit=i%4
//     r += (ci + 2^bit*na) * ((p>=npos) ? (p-npos+1)^2/2 : 0)
//     f  = staircase(r) = sum_{k=1..15} clamp(r-16k+1,0,1)   [closed form]
//     r -= 16*a*f ;  co += a*f
// All other channels pass through unchanged.
//
// v2: LDS-staged I/O. The v1 layout (lane i owns bytes [64i,64i+64)) made
// every global load/store instruction touch 32 cache lines (16B/lane over a
// 4KB window) and produced partial-line stores (WRITE_SIZE 98MB for a 64MB
// output). Here each global access is lane-contiguous (16B/lane, 1KB/instr,
// full 128B lines); the token-major view is materialized through LDS with an
// 80B/token padded layout (5 float4 slots) so the per-token ds_read_b128 /
// ds_write_b128 spread across all 32 banks (only the free 2-way aliasing).

#define TOK_THREADS 256
#define TOKENS_PER_BLOCK 256  // == TOK_THREADS: one token per thread

__device__ __forceinline__ void mul32_compute(float4& v0, float4& v1,
                                              const float4& v2, float p) {
  const float a  = v2.z;               // OPMUL
  const float na = v0.y;               // NIB_A
  const float nb = v0.z;               // NIB_B
  const float ci = v1.x;               // CARRY_IN

  // FFN0: r = r*(1-a)
  float r  = fmaf(-a, v0.w, v0.w);
  float co = v1.y;
  float t  = v1.z;

  // TEMP closed form: nb * (1+1/2+1/4+1/8) * (p+1)^2/2
  t = fmaf(nb * 0.9375f, (p + 1.f) * (p + 1.f), t);

  // gate per bit: ci + 2^bit * na
  const float g0 = ci + na;
  const float g1 = fmaf(2.f, na, ci);
  const float g2 = fmaf(4.f, na, ci);
  const float g3 = fmaf(8.f, na, ci);

#pragma unroll
  for (int npos = 0; npos < 8; ++npos) {
    const float d = p - (float)npos + 1.f;       // >=1 iff p>=npos, <=0 otherwise
    const float T = (d > 0.f) ? 0.5f * d * d : 0.f;
#pragma unroll
    for (int bit = 0; bit < 4; ++bit) {
      const float g = (bit == 0) ? g0 : (bit == 1) ? g1 : (bit == 2) ? g2 : g3;
      r = fmaf(g, T, r);
      // carry staircase f(r) = sum_{k=1..15} clamp(r-16k+1,0,1), r >= 0 always
      const float c    = floorf(r * 0.0625f);
      const float full = fminf(c, 15.f);
      float ramp = fminf(fmaxf(fmaf(-16.f, c, r) - 15.f, 0.f), 1.f);
      ramp = (c < 15.f) ? ramp : 0.f;
      const float f = full + ramp;
      r  = fmaf(-16.f * a, f, r);
      co = fmaf(a, f, co);
    }
  }

  v0.w = r;
  v1.y = co;
  v1.z = t;
}

__global__ __launch_bounds__(TOK_THREADS) void pure_mul32_kernel(
    const float* __restrict__ x, float* __restrict__ out, int ntok) {
  // 5 float4 slots per token: 4 data + 1 pad -> 80B stride, conflict-free
  __shared__ float4 lds[TOKENS_PER_BLOCK * 5];

  const int t = threadIdx.x;
  const int tok0 = blockIdx.x * TOKENS_PER_BLOCK;

  const float4* __restrict__ xin4 = reinterpret_cast<const float4*>(x);
  float4* __restrict__ out4 = reinterpret_cast<float4*>(out);

  if (tok0 + TOKENS_PER_BLOCK <= ntok) {
    // ---------- fast path: full block of 256 tokens ----------
    const size_t gbase = (size_t)tok0 * 4;  // float4 index of block start

    // Coalesced load: instr j covers 1KB contiguous per wave.
    // Local float4 index L = j*256 + t; token tk = L>>2, slot s = L&3.
#pragma unroll
    for (int j = 0; j < 4; ++j) {
      const int L = j * TOK_THREADS + t;
      lds[(L >> 2) * 5 + (L & 3)] = xin4[gbase + L];
    }
    __syncthreads();

    float4 v0 = lds[t * 5 + 0];  // {POS, NIB_A, NIB_B, RESULT}
    float4 v1 = lds[t * 5 + 1];  // {CARRY_IN, CARRY_OUT, TEMP, ch7}
    const float4 v2 = lds[t * 5 + 2];  // {ch8, ch9, OPMUL, ch11}

    const float p = (float)((tok0 + t) & 7);  // POS channel = arange(P)
    mul32_compute(v0, v1, v2, p);

    // Thread t's LDS slots are private to thread t in this phase: no barrier
    // needed between its own read and write-back.
    lds[t * 5 + 0] = v0;
    lds[t * 5 + 1] = v1;
    __syncthreads();

    // Coalesced store: full 128B lines per wave-pair of lanes.
#pragma unroll
    for (int j = 0; j < 4; ++j) {
      const int L = j * TOK_THREADS + t;
      out4[gbase + L] = lds[(L >> 2) * 5 + (L & 3)];
    }
  } else {
    // ---------- tail path: per-token direct (original v1 pattern) ----------
    const int idx = tok0 + t;
    if (idx >= ntok) return;

    const float4* __restrict__ xin = xin4 + (size_t)idx * 4;
    float4 v0 = xin[0];
    float4 v1 = xin[1];
    float4 v2 = xin[2];
    float4 v3 = xin[3];

    const float p = (float)(idx & 7);
    mul32_compute(v0, v1, v2, p);

    float4* __restrict__ o = out4 + (size_t)idx * 4;
    o[0] = v0; o[1] = v1; o[2] = v2; o[3] = v3;
  }
}

extern "C" void kernel_launch(void* const* d_in, const int* in_sizes, int n_in,
                              void* d_out, int out_size, void* d_ws, size_t ws_size,
                              hipStream_t stream) {
  const float* x = (const float*)d_in[0];
  float* out = (float*)d_out;
  const int ntok = in_sizes[0] / 16;  // B*P tokens, 16 channels each
  const int blocks = (ntok + TOKENS_PER_BLOCK - 1) / TOKENS_PER_BLOCK;
  pure_mul32_kernel<<<blocks, TOK_THREADS, 0, stream>>>(x, out, ntok);
}